// Round 12
// baseline (2259.470 us; speedup 1.0000x reference)
//
#include <hip/hip_runtime.h>
#include <math.h>

// Problem constants
#define B_SZ    4096
#define D_DIM   128
#define K_CODES 8192
#define RECON_N (4096*84*84)   // 28901376

// ============================ VQ argmin + losses ============================
// Exact numpy-f32 semantics (verified R2/R3): d2q = fl32(zz - 2r), r = sequential
// f32 FMA chain over d ascending, zz = numpy pairwise-8. Ties -> lowest index.
__global__ __attribute__((amdgpu_flat_work_group_size(1024,1024),
                          amdgpu_waves_per_eu(4,8)))
void vq_kernel(
    const float* __restrict__ z, const float* __restrict__ cb,
    int* __restrict__ idx_ws, float* __restrict__ out_idx_f,
    double* __restrict__ lpart)
{
  __shared__ float z_s[16][128];
  __shared__ float zz_s[16];
  __shared__ float redv[16][16];   // [wave][row]
  __shared__ int   redi[16][16];
  __shared__ int   win[16];
  __shared__ double wsum[16];
  const int t  = threadIdx.x;
  const int b0 = blockIdx.x * 16;

  for (int p = t; p < 2048; p += 1024) z_s[p >> 7][p & 127] = z[(size_t)b0*128 + p];
  __syncthreads();

  // numpy pairwise-8 emulation of (z*z).sum(axis=1); separate mul/add roundings
  if (t < 16) {
    #pragma clang fp contract(off)
    const float* a = z_s[t];
    float r8[8];
    #pragma unroll
    for (int j = 0; j < 8; j++) { float v = a[j]*a[j]; r8[j] = v; }
    for (int i = 8; i < 128; i += 8) {
      #pragma unroll
      for (int j = 0; j < 8; j++) { float v = a[i+j]*a[i+j]; r8[j] = r8[j] + v; }
    }
    zz_s[t] = ((r8[0]+r8[1]) + (r8[2]+r8[3])) + ((r8[4]+r8[5]) + (r8[6]+r8[7]));
  }
  __syncthreads();

  const int lane = t & 63, wv = t >> 6;
  float zzr[16];
  #pragma unroll
  for (int row = 0; row < 16; row++) zzr[row] = zz_s[row];

  float best[16]; int bid[16];
  #pragma unroll
  for (int row = 0; row < 16; row++) { best[row] = INFINITY; bid[row] = 0; }

  #pragma unroll 1
  for (int k = 0; k < 8; k++) {
    const int cg   = wv + (k << 4);        // 16 waves cover 128 groups of 64 codes
    const int code = (cg << 6) + lane;     // ascending in k for fixed lane
    const float* ep = cb + (size_t)code * 128;
    float r[16];
    #pragma unroll
    for (int row = 0; row < 16; row++) r[row] = 0.0f;
    #pragma unroll 1
    for (int d16 = 0; d16 < 8; d16++) {
      const float4 e0 = *(const float4*)(ep + d16*16 + 0);
      const float4 e1 = *(const float4*)(ep + d16*16 + 4);
      const float4 e2 = *(const float4*)(ep + d16*16 + 8);
      const float4 e3 = *(const float4*)(ep + d16*16 + 12);
      #pragma unroll
      for (int row = 0; row < 16; row++) {
        const float4 z0 = *(const float4*)(&z_s[row][d16*16 + 0]);   // uniform -> broadcast
        const float4 z1 = *(const float4*)(&z_s[row][d16*16 + 4]);
        const float4 z2 = *(const float4*)(&z_s[row][d16*16 + 8]);
        const float4 z3 = *(const float4*)(&z_s[row][d16*16 + 12]);
        float rr = r[row];
        // single dependent FMA chain, d ascending — identical to R3 (bit-exact)
        rr = fmaf(z0.x,e0.x,rr); rr = fmaf(z0.y,e0.y,rr); rr = fmaf(z0.z,e0.z,rr); rr = fmaf(z0.w,e0.w,rr);
        rr = fmaf(z1.x,e1.x,rr); rr = fmaf(z1.y,e1.y,rr); rr = fmaf(z1.z,e1.z,rr); rr = fmaf(z1.w,e1.w,rr);
        rr = fmaf(z2.x,e2.x,rr); rr = fmaf(z2.y,e2.y,rr); rr = fmaf(z2.z,e2.z,rr); rr = fmaf(z2.w,e2.w,rr);
        rr = fmaf(z3.x,e3.x,rr); rr = fmaf(z3.y,e3.y,rr); rr = fmaf(z3.z,e3.z,rr); rr = fmaf(z3.w,e3.w,rr);
        r[row] = rr;
      }
    }
    #pragma unroll
    for (int row = 0; row < 16; row++) {
      const float tt = fmaf(-2.0f, r[row], zzr[row]);  // fl32(zz - 2r), single rounding
      if (tt < best[row]) { best[row] = tt; bid[row] = code; }
    }
  }

  // cross-lane lex argmin per row (tie -> smaller index)
  #pragma unroll 1
  for (int row = 0; row < 16; row++) {
    float v = best[row]; int i = bid[row];
    #pragma unroll
    for (int m = 32; m; m >>= 1) {
      float v2 = __shfl_xor(v, m, 64);
      int   i2 = __shfl_xor(i, m, 64);
      if (v2 < v || (v2 == v && i2 < i)) { v = v2; i = i2; }
    }
    if (lane == 0) { redv[wv][row] = v; redi[wv][row] = i; }
  }
  __syncthreads();

  if (t < 16) {   // row t: reduce over 16 waves
    float v = redv[0][t]; int i = redi[0][t];
    #pragma unroll 1
    for (int w = 1; w < 16; w++) {
      float v2 = redv[w][t]; int i2 = redi[w][t];
      if (v2 < v || (v2 == v && i2 < i)) { v = v2; i = i2; }
    }
    win[t] = i;
    idx_ws[b0 + t] = i;
    out_idx_f[b0 + t] = (float)i;   // float out; exact for idx < 2^24
  }
  __syncthreads();

  // loss partial: sum (z - e_win)^2 over 16 rows (f64; threshold slack huge)
  double ls = 0.0;
  for (int p = t; p < 2048; p += 1024) {
    int r = p >> 7, d = p & 127;
    float diff = z_s[r][d] - cb[(size_t)win[r]*128 + d];
    ls = fma((double)diff, (double)diff, ls);
  }
  #pragma unroll
  for (int m = 32; m; m >>= 1) ls += __shfl_xor(ls, m, 64);
  if (lane == 0) wsum[wv] = ls;
  __syncthreads();
  if (t == 0) {
    double s = 0.0;
    for (int w = 0; w < 16; w++) s += wsum[w];
    lpart[blockIdx.x] = s;
  }
}

__global__ __launch_bounds__(256) void fin_kernel(const double* __restrict__ lpart,
                                                  float* __restrict__ out_loss)
{
  __shared__ double s[256];
  const int t = threadIdx.x;
  s[t] = lpart[t];
  __syncthreads();
  for (int off = 128; off; off >>= 1) {
    if (t < off) s[t] += s[t + off];
    __syncthreads();
  }
  if (t == 0) {
    float l = (float)(s[0] / (4096.0*128.0));
    out_loss[0] = l;   // codebook_loss
    out_loss[1] = l;   // commitment_loss (same value)
  }
}

// ===================== linear: x1[b,o] = cb[idx[b]] . lin_w[o] + lin_b[o] ====
__global__ __launch_bounds__(256) void linear_kernel(
    const float* __restrict__ cb, const int* __restrict__ idx,
    const float* __restrict__ lw, const float* __restrict__ lb,
    float* __restrict__ x1)
{
  __shared__ float As[64][65];
  __shared__ float Bs[64][65];
  __shared__ int idx_s[64];
  const int t  = threadIdx.x;
  const int b0 = blockIdx.x * 64, n0 = blockIdx.y * 64;
  if (t < 64) idx_s[t] = idx[b0 + t];
  float acc[4][4] = {{0.f}};
  const int tr = (t >> 4)*4, tc = (t & 15)*4;
  for (int d0 = 0; d0 < 128; d0 += 64) {
    __syncthreads();
    #pragma unroll
    for (int l = 0; l < 16; l++) {
      int flat = t + l*256;
      int r = flat >> 6, d = flat & 63;
      As[r][d] = cb[(size_t)idx_s[r]*128 + d0 + d];
      Bs[r][d] = lw[(size_t)(n0 + r)*128 + d0 + d];
    }
    __syncthreads();
    #pragma unroll 8
    for (int d = 0; d < 64; d++) {
      float a0 = As[tr+0][d], a1 = As[tr+1][d], a2 = As[tr+2][d], a3 = As[tr+3][d];
      float q0 = Bs[tc+0][d], q1 = Bs[tc+1][d], q2 = Bs[tc+2][d], q3 = Bs[tc+3][d];
      acc[0][0] = fmaf(a0,q0,acc[0][0]); acc[0][1] = fmaf(a0,q1,acc[0][1]);
      acc[0][2] = fmaf(a0,q2,acc[0][2]); acc[0][3] = fmaf(a0,q3,acc[0][3]);
      acc[1][0] = fmaf(a1,q0,acc[1][0]); acc[1][1] = fmaf(a1,q1,acc[1][1]);
      acc[1][2] = fmaf(a1,q2,acc[1][2]); acc[1][3] = fmaf(a1,q3,acc[1][3]);
      acc[2][0] = fmaf(a2,q0,acc[2][0]); acc[2][1] = fmaf(a2,q1,acc[2][1]);
      acc[2][2] = fmaf(a2,q2,acc[2][2]); acc[2][3] = fmaf(a2,q3,acc[2][3]);
      acc[3][0] = fmaf(a3,q0,acc[3][0]); acc[3][1] = fmaf(a3,q1,acc[3][1]);
      acc[3][2] = fmaf(a3,q2,acc[3][2]); acc[3][3] = fmaf(a3,q3,acc[3][3]);
    }
  }
  #pragma unroll
  for (int i = 0; i < 4; i++)
    #pragma unroll
    for (int j = 0; j < 4; j++)
      x1[(size_t)(b0 + tr + i)*3136 + n0 + tc + j] = acc[i][j] + lb[n0 + tc + j];
}

// ========== decoder_f: FUSED conv1+conv2+conv3+resize+tanh, 1 img/block ======
// R12 == R11 resubmitted (bench infra failed twice; kernel re-audited: no OOB,
// no divergent barriers, LDS aliasing barrier-ordered, 114944B <= cap).
// Rationale: decoder_a is pinned at ~1520-1555us across 7 structural variants
// (occupancy wall: 14 waves/1 block/CU; allocator wall: spills past ~64 arch
// VGPRs). Remaining slack is decoder_b (~350us) + chunk serialization + a2
// traffic. After conv2 the block holds the ENTIRE conv2 output in registers
// (896 thr x 28 acc = 25088 fl = one image) and the conv1 planes in LDS are
// dead -> write acc into LDS ALIASING the planes region, run conv3+resize+
// tanh in-kernel. Eliminates a2 write (407MB) + re-read (411MB) + decoder_b.
// Cost: conv1 loses 2-image weight amortization. FMA chains identical ->
// absmax unchanged.
// LDS: planes [0..16640) aliased by Cs [0..25088); Ds at 25088; W3s at 28224.
#define DF_T 896
#define B1_CS 260                  // plane row-block stride; %32==4
#define PLANES_FL (64*B1_CS)       // 16640 floats
#define DF_LDS_FL (25088+3136+512) // 28736 floats = 114944 B
__global__ __attribute__((amdgpu_flat_work_group_size(DF_T, DF_T),
                          amdgpu_waves_per_eu(4, 4)))
void decoder_f(
    const float* __restrict__ x1,
    const float* __restrict__ w1, const float* __restrict__ b1,
    const float* __restrict__ w2, const float* __restrict__ b2,
    const float* __restrict__ w3, const float* __restrict__ b3,
    float* __restrict__ out)
{
  extern __shared__ float lds[];
  float* Ds  = lds + 25088;
  float* W3s = lds + 28224;
  const int tid = threadIdx.x;
  const int bg  = blockIdx.x;      // image index (grid == 4096)

  for (int p = tid; p < PLANES_FL; p += DF_T) lds[p] = 0.0f;
  for (int p = tid; p < 512; p += DF_T) W3s[p] = w3[p];   // region beyond planes
  __syncthreads();

  // ---- conv1: (64,7,7) -> (64,14,14), relu. item = (c=tid&63, y=tid>>6) ----
  {
    const int c = tid & 63, y = tid >> 6;
    const int ky0 = (y & 1) ? 0 : 1;
    const int iy0 = (y + 1 - ky0) >> 1;   // valid if <7
    const int iy1 = iy0 - 1;              // valid if >=0
    const bool v0 = (iy0 < 7), v1 = (iy1 >= 0);   // wave-uniform (y = wave idx)
    float acc[14];
    const float bias = b1[c];
    #pragma unroll
    for (int x = 0; x < 14; x++) acc[x] = bias;
    const float* xim = x1 + (size_t)bg*3136;
    #pragma unroll 1
    for (int i = 0; i < 64; i++) {
      const float* wp = w1 + (((i << 6) + c) << 4) + ky0*4;
      const float4 wA4 = *(const float4*)(wp);
      const float4 wB4 = *(const float4*)(wp + 8);
      const float wa[4] = {wA4.x, wA4.y, wA4.z, wA4.w};
      const float wb[4] = {wB4.x, wB4.y, wB4.z, wB4.w};
      float r0[7], r1[7];
      if (v0) {
        const float* xr = xim + i*49 + iy0*7;
        #pragma unroll
        for (int j = 0; j < 7; j++) r0[j] = xr[j];
      } else {
        #pragma unroll
        for (int j = 0; j < 7; j++) r0[j] = 0.0f;
      }
      if (v1) {
        const float* xr = xim + i*49 + iy1*7;
        #pragma unroll
        for (int j = 0; j < 7; j++) r1[j] = xr[j];
      } else {
        #pragma unroll
        for (int j = 0; j < 7; j++) r1[j] = 0.0f;
      }
      #pragma unroll
      for (int x = 0; x < 14; x++) {
        const int kxs = (x & 1) ? 0 : 1;
        const int ix0 = (x + 1 - kxs) >> 1;
        const int ix1 = ix0 - 1;
        float s = acc[x];
        if (ix0 < 7)  { s = fmaf(r0[ix0], wa[kxs],   s); s = fmaf(r1[ix0], wb[kxs],   s); }
        if (ix1 >= 0) { s = fmaf(r0[ix1], wa[kxs+2], s); s = fmaf(r1[ix1], wb[kxs+2], s); }
        acc[x] = s;
      }
    }
    // write interior of halo plane: row y+1, cols 1..14
    float* o = &lds[c*B1_CS + (y + 1)*16 + 1];
    #pragma unroll
    for (int x = 0; x < 14; x++) o[x] = fmaxf(acc[x], 0.0f);
  }
  __syncthreads();

  // ---- conv2: (64,14,14) -> (32,28,28), relu -> REGISTERS ----
  // item = (c=tid&31, y=tid>>5); full 28-wide row; b128 LDS reads (R4 form)
  float c2acc[28];
  const int c2c = tid & 31, c2y = tid >> 5;
  {
    const int c = c2c, y = c2y;
    const int ky0 = (y & 1) ? 0 : 1;
    const int iy0 = (y + 1 - ky0) >> 1;     // 0..14
    const int row0 = iy0 + 1;               // halo row for ky0   (1..15)
    const int row1 = iy0;                   // halo row for ky0+2 (0..14)
    const float bias = b2[c];
    #pragma unroll
    for (int x = 0; x < 28; x++) c2acc[x] = bias;
    #pragma unroll 1
    for (int i = 0; i < 64; i++) {
      const float* wp = w2 + (((i << 5) + c) << 4) + ky0*4;
      const float4 wA4 = *(const float4*)(wp);
      const float4 wB4 = *(const float4*)(wp + 8);
      const float wa[4] = {wA4.x, wA4.y, wA4.z, wA4.w};
      const float wb[4] = {wB4.x, wB4.y, wB4.z, wB4.w};
      const float* rp0 = lds + i*B1_CS + row0*16;
      const float* rp1 = lds + i*B1_CS + row1*16;
      float r0[16], r1[16];
      #pragma unroll
      for (int q = 0; q < 4; q++) {
        const float4 a4 = *(const float4*)(rp0 + q*4);
        r0[q*4+0]=a4.x; r0[q*4+1]=a4.y; r0[q*4+2]=a4.z; r0[q*4+3]=a4.w;
      }
      #pragma unroll
      for (int q = 0; q < 4; q++) {
        const float4 a4 = *(const float4*)(rp1 + q*4);
        r1[q*4+0]=a4.x; r1[q*4+1]=a4.y; r1[q*4+2]=a4.z; r1[q*4+3]=a4.w;
      }
      #pragma unroll
      for (int x = 0; x < 28; x++) {
        const int kxs = (x & 1) ? 0 : 1;
        const int col = ((x + 1 - kxs) >> 1) + 1;   // 1..15
        float s = c2acc[x];
        s = fmaf(r0[col],   wa[kxs],   s);
        s = fmaf(r1[col],   wb[kxs],   s);
        s = fmaf(r0[col-1], wa[kxs+2], s);
        s = fmaf(r1[col-1], wb[kxs+2], s);
        c2acc[x] = s;
      }
    }
    #pragma unroll
    for (int x = 0; x < 28; x++) c2acc[x] = fmaxf(c2acc[x], 0.0f);
  }
  __syncthreads();   // all plane reads complete -> safe to alias

  // ---- write conv2 output into Cs (aliases dead planes region) ----
  {
    float* st = lds + c2c*784 + c2y*28;   // 16B aligned (784%4==0, 28%4==0)
    #pragma unroll
    for (int q = 0; q < 7; q++)
      *(float4*)(st + q*4) = make_float4(c2acc[q*4+0],c2acc[q*4+1],c2acc[q*4+2],c2acc[q*4+3]);
  }
  __syncthreads();

  // ---- conv3: (32,28,28) -> (1,56,56) into Ds ----
  if (tid < 784) {   // item = (y=tid/14 in 0..55, xq=tid%14), 4 px each
    const int y = tid / 14, xq = tid - y*14;
    const int x0 = xq * 4;
    const int ky0 = (y & 1) ? 0 : 1;
    const int iy0 = (y + 1 - ky0) >> 1;   // valid if <28
    const int iy1 = iy0 - 1;              // valid if >=0
    const bool v0 = (iy0 < 28), v1 = (iy1 >= 0);
    const int ixb = (x0 >> 1) - 1;        // input col for j=0
    float acc[4];
    const float bias = b3[0];
    #pragma unroll
    for (int x = 0; x < 4; x++) acc[x] = bias;
    #pragma unroll 1
    for (int i = 0; i < 32; i++) {
      const float* wr = &W3s[i*16 + ky0*4];
      float wa[4], wb[4];
      #pragma unroll
      for (int k = 0; k < 4; k++) { wa[k] = wr[k]; wb[k] = wr[8 + k]; }
      const float* Ci = lds + i*784;
      float r0[4], r1[4];
      #pragma unroll
      for (int j = 0; j < 4; j++) {
        const int ix = ixb + j;
        const bool vx = (ix >= 0) && (ix < 28);
        r0[j] = (v0 && vx) ? Ci[iy0*28 + ix] : 0.0f;
        r1[j] = (v1 && vx) ? Ci[iy1*28 + ix] : 0.0f;
      }
      #pragma unroll
      for (int xl = 0; xl < 4; xl++) {
        const int kxs = (xl & 1) ? 0 : 1;     // x0 even
        const int j = ((x0 + xl + 1 - kxs) >> 1) - ixb;   // 1..3
        float s = acc[xl];
        s = fmaf(r0[j],   wa[kxs],   s);
        s = fmaf(r1[j],   wb[kxs],   s);
        s = fmaf(r0[j-1], wa[kxs+2], s);
        s = fmaf(r1[j-1], wb[kxs+2], s);
        acc[xl] = s;
      }
    }
    *(float4*)(&Ds[y*56 + x0]) = make_float4(acc[0],acc[1],acc[2],acc[3]);
  }
  __syncthreads();

  // ---- bilinear resize 56->84 (half-pixel, edge clamp) + tanh ----
  for (int p = tid; p < 84*84; p += DF_T) {
    const int oy = p / 84, ox = p - oy*84;
    const float sy = (oy + 0.5f)*(2.0f/3.0f) - 0.5f;
    const float sx = (ox + 0.5f)*(2.0f/3.0f) - 0.5f;
    const int y0 = (int)floorf(sy), x0i = (int)floorf(sx);
    const float fy = sy - (float)y0, fx = sx - (float)x0i;
    const int y0c = y0 < 0 ? 0 : y0, y1c = (y0 + 1 > 55) ? 55 : (y0 + 1);
    const int x0c = x0i < 0 ? 0 : x0i, x1c = (x0i + 1 > 55) ? 55 : (x0i + 1);
    const float v00 = Ds[y0c*56 + x0c], v01 = Ds[y0c*56 + x1c];
    const float v10 = Ds[y1c*56 + x0c], v11 = Ds[y1c*56 + x1c];
    const float v = (v00*(1.0f - fx) + v01*fx)*(1.0f - fy)
                  + (v10*(1.0f - fx) + v11*fx)*fy;
    out[(size_t)bg*7056 + p] = tanhf(v);
  }
}

// ================================ launch ====================================
extern "C" void kernel_launch(void* const* d_in, const int* in_sizes, int n_in,
                              void* d_out, int out_size, void* d_ws, size_t ws_size,
                              hipStream_t stream) {
  (void)in_sizes; (void)n_in; (void)out_size; (void)ws_size;
  const float* z  = (const float*)d_in[0];
  const float* cb = (const float*)d_in[1];
  const float* lw = (const float*)d_in[2];
  const float* lb = (const float*)d_in[3];
  const float* w1 = (const float*)d_in[4];
  const float* b1 = (const float*)d_in[5];
  const float* w2 = (const float*)d_in[6];
  const float* b2 = (const float*)d_in[7];
  const float* w3 = (const float*)d_in[8];
  const float* b3 = (const float*)d_in[9];

  float* out      = (float*)d_out;
  float* out_idx  = out + RECON_N;          // 4096 indices as float
  float* out_loss = out + RECON_N + 4096;   // 2 losses

  char*   ws     = (char*)d_ws;
  double* lpart  = (double*)ws;             // 256 doubles
  int*    idx_ws = (int*)(ws + 4096);       // 4096 ints
  float*  x1     = (float*)(ws + 32768);    // 4096*3136 floats (51.4 MB)

  vq_kernel<<<256, 1024, 0, stream>>>(z, cb, idx_ws, out_idx, lpart);
  fin_kernel<<<1, 256, 0, stream>>>(lpart, out_loss);
  linear_kernel<<<dim3(64, 49), 256, 0, stream>>>(cb, idx_ws, lw, lb, x1);

  const int df_lds = DF_LDS_FL*4;          // 114944 B
  hipFuncSetAttribute((const void*)decoder_f,
                      hipFuncAttributeMaxDynamicSharedMemorySize, df_lds);
  decoder_f<<<B_SZ, DF_T, df_lds, stream>>>(x1, w1, b1, w2, b2, w3, b3, out);
}

// Round 13
// 2240.675 us; speedup vs baseline: 1.0084x; 1.0084x over previous
//
#include <hip/hip_runtime.h>
#include <math.h>

// Problem constants
#define B_SZ    4096
#define D_DIM   128
#define K_CODES 8192
#define RECON_N (4096*84*84)   // 28901376

// ============================ VQ argmin + losses ============================
// Exact numpy-f32 semantics (verified R2/R3): d2q = fl32(zz - 2r), r = sequential
// f32 FMA chain over d ascending, zz = numpy pairwise-8. Ties -> lowest index.
__global__ __attribute__((amdgpu_flat_work_group_size(1024,1024),
                          amdgpu_waves_per_eu(4,8)))
void vq_kernel(
    const float* __restrict__ z, const float* __restrict__ cb,
    int* __restrict__ idx_ws, float* __restrict__ out_idx_f,
    double* __restrict__ lpart)
{
  __shared__ float z_s[16][128];
  __shared__ float zz_s[16];
  __shared__ float redv[16][16];   // [wave][row]
  __shared__ int   redi[16][16];
  __shared__ int   win[16];
  __shared__ double wsum[16];
  const int t  = threadIdx.x;
  const int b0 = blockIdx.x * 16;

  for (int p = t; p < 2048; p += 1024) z_s[p >> 7][p & 127] = z[(size_t)b0*128 + p];
  __syncthreads();

  // numpy pairwise-8 emulation of (z*z).sum(axis=1); separate mul/add roundings
  if (t < 16) {
    #pragma clang fp contract(off)
    const float* a = z_s[t];
    float r8[8];
    #pragma unroll
    for (int j = 0; j < 8; j++) { float v = a[j]*a[j]; r8[j] = v; }
    for (int i = 8; i < 128; i += 8) {
      #pragma unroll
      for (int j = 0; j < 8; j++) { float v = a[i+j]*a[i+j]; r8[j] = r8[j] + v; }
    }
    zz_s[t] = ((r8[0]+r8[1]) + (r8[2]+r8[3])) + ((r8[4]+r8[5]) + (r8[6]+r8[7]));
  }
  __syncthreads();

  const int lane = t & 63, wv = t >> 6;
  float zzr[16];
  #pragma unroll
  for (int row = 0; row < 16; row++) zzr[row] = zz_s[row];

  float best[16]; int bid[16];
  #pragma unroll
  for (int row = 0; row < 16; row++) { best[row] = INFINITY; bid[row] = 0; }

  #pragma unroll 1
  for (int k = 0; k < 8; k++) {
    const int cg   = wv + (k << 4);        // 16 waves cover 128 groups of 64 codes
    const int code = (cg << 6) + lane;     // ascending in k for fixed lane
    const float* ep = cb + (size_t)code * 128;
    float r[16];
    #pragma unroll
    for (int row = 0; row < 16; row++) r[row] = 0.0f;
    #pragma unroll 1
    for (int d16 = 0; d16 < 8; d16++) {
      const float4 e0 = *(const float4*)(ep + d16*16 + 0);
      const float4 e1 = *(const float4*)(ep + d16*16 + 4);
      const float4 e2 = *(const float4*)(ep + d16*16 + 8);
      const float4 e3 = *(const float4*)(ep + d16*16 + 12);
      #pragma unroll
      for (int row = 0; row < 16; row++) {
        const float4 z0 = *(const float4*)(&z_s[row][d16*16 + 0]);   // uniform -> broadcast
        const float4 z1 = *(const float4*)(&z_s[row][d16*16 + 4]);
        const float4 z2 = *(const float4*)(&z_s[row][d16*16 + 8]);
        const float4 z3 = *(const float4*)(&z_s[row][d16*16 + 12]);
        float rr = r[row];
        // single dependent FMA chain, d ascending — identical to R3 (bit-exact)
        rr = fmaf(z0.x,e0.x,rr); rr = fmaf(z0.y,e0.y,rr); rr = fmaf(z0.z,e0.z,rr); rr = fmaf(z0.w,e0.w,rr);
        rr = fmaf(z1.x,e1.x,rr); rr = fmaf(z1.y,e1.y,rr); rr = fmaf(z1.z,e1.z,rr); rr = fmaf(z1.w,e1.w,rr);
        rr = fmaf(z2.x,e2.x,rr); rr = fmaf(z2.y,e2.y,rr); rr = fmaf(z2.z,e2.z,rr); rr = fmaf(z2.w,e2.w,rr);
        rr = fmaf(z3.x,e3.x,rr); rr = fmaf(z3.y,e3.y,rr); rr = fmaf(z3.z,e3.z,rr); rr = fmaf(z3.w,e3.w,rr);
        r[row] = rr;
      }
    }
    #pragma unroll
    for (int row = 0; row < 16; row++) {
      const float tt = fmaf(-2.0f, r[row], zzr[row]);  // fl32(zz - 2r), single rounding
      if (tt < best[row]) { best[row] = tt; bid[row] = code; }
    }
  }

  // cross-lane lex argmin per row (tie -> smaller index)
  #pragma unroll 1
  for (int row = 0; row < 16; row++) {
    float v = best[row]; int i = bid[row];
    #pragma unroll
    for (int m = 32; m; m >>= 1) {
      float v2 = __shfl_xor(v, m, 64);
      int   i2 = __shfl_xor(i, m, 64);
      if (v2 < v || (v2 == v && i2 < i)) { v = v2; i = i2; }
    }
    if (lane == 0) { redv[wv][row] = v; redi[wv][row] = i; }
  }
  __syncthreads();

  if (t < 16) {   // row t: reduce over 16 waves
    float v = redv[0][t]; int i = redi[0][t];
    #pragma unroll 1
    for (int w = 1; w < 16; w++) {
      float v2 = redv[w][t]; int i2 = redi[w][t];
      if (v2 < v || (v2 == v && i2 < i)) { v = v2; i = i2; }
    }
    win[t] = i;
    idx_ws[b0 + t] = i;
    out_idx_f[b0 + t] = (float)i;   // float out; exact for idx < 2^24
  }
  __syncthreads();

  // loss partial: sum (z - e_win)^2 over 16 rows (f64; threshold slack huge)
  double ls = 0.0;
  for (int p = t; p < 2048; p += 1024) {
    int r = p >> 7, d = p & 127;
    float diff = z_s[r][d] - cb[(size_t)win[r]*128 + d];
    ls = fma((double)diff, (double)diff, ls);
  }
  #pragma unroll
  for (int m = 32; m; m >>= 1) ls += __shfl_xor(ls, m, 64);
  if (lane == 0) wsum[wv] = ls;
  __syncthreads();
  if (t == 0) {
    double s = 0.0;
    for (int w = 0; w < 16; w++) s += wsum[w];
    lpart[blockIdx.x] = s;
  }
}

__global__ __launch_bounds__(256) void fin_kernel(const double* __restrict__ lpart,
                                                  float* __restrict__ out_loss)
{
  __shared__ double s[256];
  const int t = threadIdx.x;
  s[t] = lpart[t];
  __syncthreads();
  for (int off = 128; off; off >>= 1) {
    if (t < off) s[t] += s[t + off];
    __syncthreads();
  }
  if (t == 0) {
    float l = (float)(s[0] / (4096.0*128.0));
    out_loss[0] = l;   // codebook_loss
    out_loss[1] = l;   // commitment_loss (same value)
  }
}

// ===================== linear: x1p[b, c,y,x padded] = cb[idx[b]].lin_w + lb ==
// R13: output written in PADDED layout [img][c][y*8][x(8)] (4096 fl/img) so
// decoder_f's conv1 can load rows as aligned float4 pairs. Pad lane (x=7) is
// never read. Same dot products, same values; only the store addresses change.
__global__ __launch_bounds__(256) void linear_kernel(
    const float* __restrict__ cb, const int* __restrict__ idx,
    const float* __restrict__ lw, const float* __restrict__ lb,
    float* __restrict__ x1p)
{
  __shared__ float As[64][65];
  __shared__ float Bs[64][65];
  __shared__ int idx_s[64];
  const int t  = threadIdx.x;
  const int b0 = blockIdx.x * 64, n0 = blockIdx.y * 64;
  if (t < 64) idx_s[t] = idx[b0 + t];
  float acc[4][4] = {{0.f}};
  const int tr = (t >> 4)*4, tc = (t & 15)*4;
  for (int d0 = 0; d0 < 128; d0 += 64) {
    __syncthreads();
    #pragma unroll
    for (int l = 0; l < 16; l++) {
      int flat = t + l*256;
      int r = flat >> 6, d = flat & 63;
      As[r][d] = cb[(size_t)idx_s[r]*128 + d0 + d];
      Bs[r][d] = lw[(size_t)(n0 + r)*128 + d0 + d];
    }
    __syncthreads();
    #pragma unroll 8
    for (int d = 0; d < 64; d++) {
      float a0 = As[tr+0][d], a1 = As[tr+1][d], a2 = As[tr+2][d], a3 = As[tr+3][d];
      float q0 = Bs[tc+0][d], q1 = Bs[tc+1][d], q2 = Bs[tc+2][d], q3 = Bs[tc+3][d];
      acc[0][0] = fmaf(a0,q0,acc[0][0]); acc[0][1] = fmaf(a0,q1,acc[0][1]);
      acc[0][2] = fmaf(a0,q2,acc[0][2]); acc[0][3] = fmaf(a0,q3,acc[0][3]);
      acc[1][0] = fmaf(a1,q0,acc[1][0]); acc[1][1] = fmaf(a1,q1,acc[1][1]);
      acc[1][2] = fmaf(a1,q2,acc[1][2]); acc[1][3] = fmaf(a1,q3,acc[1][3]);
      acc[2][0] = fmaf(a2,q0,acc[2][0]); acc[2][1] = fmaf(a2,q1,acc[2][1]);
      acc[2][2] = fmaf(a2,q2,acc[2][2]); acc[2][3] = fmaf(a2,q3,acc[2][3]);
      acc[3][0] = fmaf(a3,q0,acc[3][0]); acc[3][1] = fmaf(a3,q1,acc[3][1]);
      acc[3][2] = fmaf(a3,q2,acc[3][2]); acc[3][3] = fmaf(a3,q3,acc[3][3]);
    }
  }
  #pragma unroll
  for (int i = 0; i < 4; i++)
    #pragma unroll
    for (int j = 0; j < 4; j++) {
      const int n  = n0 + tc + j;
      const int cc = n / 49;
      const int rm = n - cc*49;
      const int yy = rm / 7;
      const int xx = rm - yy*7;
      x1p[(size_t)(b0 + tr + i)*4096 + cc*64 + yy*8 + xx] = acc[i][j] + lb[n];
    }
}

// ========== decoder_f: FUSED conv1+conv2+conv3+resize+tanh, 1 img/block ======
// R13: R12's fused kernel with its two MEASURED inefficiencies fixed:
//  * conv1 was ~50x its FMA floor — 14 scalar wave-uniform row loads per i
//    (rows at i*49+iy*7, never 16B-aligned). x1 is now PADDED [c][8y][8x]
//    (written by linear_kernel) -> each row = 2 aligned float4 loads; loads
//    per i: 14 scalar -> 4 vector.
//  * Cs stride 784 = 16 mod 32 -> 16-way conflict on float4 stores (39.1M
//    cycles in R12). Stride 786 (=2 mod 4) with float2 stores: bank pattern
//    c*18 mod 32, gcd 2 -> 16 distinct banks -> 2-way = free (m136).
// All FMA chains identical -> absmax unchanged.
// LDS: planes [0..16640) aliased by Cs [0..25152); Ds at 25152; W3s at 28288.
#define DF_T 896
#define B1_CS 260                  // conv1 plane stride; %32==4
#define PLANES_FL (64*B1_CS)       // 16640 floats
#define CS_C 786                   // Cs channel stride (floats); %32==18 -> 2-way
#define DF_LDS_FL (32*CS_C + 3136 + 512)   // 28800 floats = 115200 B
__global__ __attribute__((amdgpu_flat_work_group_size(DF_T, DF_T),
                          amdgpu_waves_per_eu(4, 4)))
void decoder_f(
    const float* __restrict__ x1p,
    const float* __restrict__ w1, const float* __restrict__ b1,
    const float* __restrict__ w2, const float* __restrict__ b2,
    const float* __restrict__ w3, const float* __restrict__ b3,
    float* __restrict__ out)
{
  extern __shared__ float lds[];
  float* Ds  = lds + 32*CS_C;            // 25152
  float* W3s = lds + 32*CS_C + 3136;     // 28288
  const int tid = threadIdx.x;
  const int bg  = blockIdx.x;      // image index (grid == 4096)

  for (int p = tid; p < PLANES_FL; p += DF_T) lds[p] = 0.0f;
  for (int p = tid; p < 512; p += DF_T) W3s[p] = w3[p];   // region beyond planes
  __syncthreads();

  // ---- conv1: (64,7,7pad8) -> (64,14,14), relu. item = (c=tid&63, y=tid>>6) --
  {
    const int c = tid & 63, y = tid >> 6;
    const int ky0 = (y & 1) ? 0 : 1;
    const int iy0 = (y + 1 - ky0) >> 1;   // valid if <7
    const int iy1 = iy0 - 1;              // valid if >=0
    const bool v0 = (iy0 < 7), v1 = (iy1 >= 0);   // wave-uniform (y = wave idx)
    float acc[14];
    const float bias = b1[c];
    #pragma unroll
    for (int x = 0; x < 14; x++) acc[x] = bias;
    const float* xim = x1p + (size_t)bg*4096;
    #pragma unroll 1
    for (int i = 0; i < 64; i++) {
      const float* wp = w1 + (((i << 6) + c) << 4) + ky0*4;
      const float4 wA4 = *(const float4*)(wp);
      const float4 wB4 = *(const float4*)(wp + 8);
      const float wa[4] = {wA4.x, wA4.y, wA4.z, wA4.w};
      const float wb[4] = {wB4.x, wB4.y, wB4.z, wB4.w};
      float r0[7], r1[7];
      if (v0) {
        const float* xr = xim + (i << 6) + iy0*8;     // 16B-aligned padded row
        const float4 q0 = *(const float4*)(xr);
        const float4 q1 = *(const float4*)(xr + 4);
        r0[0]=q0.x; r0[1]=q0.y; r0[2]=q0.z; r0[3]=q0.w;
        r0[4]=q1.x; r0[5]=q1.y; r0[6]=q1.z;           // q1.w = pad, unused
      } else {
        #pragma unroll
        for (int j = 0; j < 7; j++) r0[j] = 0.0f;
      }
      if (v1) {
        const float* xr = xim + (i << 6) + iy1*8;
        const float4 q0 = *(const float4*)(xr);
        const float4 q1 = *(const float4*)(xr + 4);
        r1[0]=q0.x; r1[1]=q0.y; r1[2]=q0.z; r1[3]=q0.w;
        r1[4]=q1.x; r1[5]=q1.y; r1[6]=q1.z;
      } else {
        #pragma unroll
        for (int j = 0; j < 7; j++) r1[j] = 0.0f;
      }
      #pragma unroll
      for (int x = 0; x < 14; x++) {
        const int kxs = (x & 1) ? 0 : 1;
        const int ix0 = (x + 1 - kxs) >> 1;
        const int ix1 = ix0 - 1;
        float s = acc[x];
        if (ix0 < 7)  { s = fmaf(r0[ix0], wa[kxs],   s); s = fmaf(r1[ix0], wb[kxs],   s); }
        if (ix1 >= 0) { s = fmaf(r0[ix1], wa[kxs+2], s); s = fmaf(r1[ix1], wb[kxs+2], s); }
        acc[x] = s;
      }
    }
    // write interior of halo plane: row y+1, cols 1..14
    float* o = &lds[c*B1_CS + (y + 1)*16 + 1];
    #pragma unroll
    for (int x = 0; x < 14; x++) o[x] = fmaxf(acc[x], 0.0f);
  }
  __syncthreads();

  // ---- conv2: (64,14,14) -> (32,28,28), relu -> REGISTERS ----
  // item = (c=tid&31, y=tid>>5); full 28-wide row; b128 LDS reads (R4 form)
  float c2acc[28];
  const int c2c = tid & 31, c2y = tid >> 5;
  {
    const int c = c2c, y = c2y;
    const int ky0 = (y & 1) ? 0 : 1;
    const int iy0 = (y + 1 - ky0) >> 1;     // 0..14
    const int row0 = iy0 + 1;               // halo row for ky0   (1..15)
    const int row1 = iy0;                   // halo row for ky0+2 (0..14)
    const float bias = b2[c];
    #pragma unroll
    for (int x = 0; x < 28; x++) c2acc[x] = bias;
    #pragma unroll 1
    for (int i = 0; i < 64; i++) {
      const float* wp = w2 + (((i << 5) + c) << 4) + ky0*4;
      const float4 wA4 = *(const float4*)(wp);
      const float4 wB4 = *(const float4*)(wp + 8);
      const float wa[4] = {wA4.x, wA4.y, wA4.z, wA4.w};
      const float wb[4] = {wB4.x, wB4.y, wB4.z, wB4.w};
      const float* rp0 = lds + i*B1_CS + row0*16;
      const float* rp1 = lds + i*B1_CS + row1*16;
      float r0[16], r1[16];
      #pragma unroll
      for (int q = 0; q < 4; q++) {
        const float4 a4 = *(const float4*)(rp0 + q*4);
        r0[q*4+0]=a4.x; r0[q*4+1]=a4.y; r0[q*4+2]=a4.z; r0[q*4+3]=a4.w;
      }
      #pragma unroll
      for (int q = 0; q < 4; q++) {
        const float4 a4 = *(const float4*)(rp1 + q*4);
        r1[q*4+0]=a4.x; r1[q*4+1]=a4.y; r1[q*4+2]=a4.z; r1[q*4+3]=a4.w;
      }
      #pragma unroll
      for (int x = 0; x < 28; x++) {
        const int kxs = (x & 1) ? 0 : 1;
        const int col = ((x + 1 - kxs) >> 1) + 1;   // 1..15
        float s = c2acc[x];
        s = fmaf(r0[col],   wa[kxs],   s);
        s = fmaf(r1[col],   wb[kxs],   s);
        s = fmaf(r0[col-1], wa[kxs+2], s);
        s = fmaf(r1[col-1], wb[kxs+2], s);
        c2acc[x] = s;
      }
    }
    #pragma unroll
    for (int x = 0; x < 28; x++) c2acc[x] = fmaxf(c2acc[x], 0.0f);
  }
  __syncthreads();   // all plane reads complete -> safe to alias

  // ---- write conv2 output into Cs (aliases dead planes region) ----
  // stride CS_C=786: float2 stores, bank pattern c*18 mod 32 -> 2-way (free)
  {
    float* st = lds + c2c*CS_C + c2y*28;
    #pragma unroll
    for (int q = 0; q < 14; q++)
      *(float2*)(st + q*2) = make_float2(c2acc[q*2+0], c2acc[q*2+1]);
  }
  __syncthreads();

  // ---- conv3: (32,28,28) -> (1,56,56) into Ds ----
  if (tid < 784) {   // item = (y=tid/14 in 0..55, xq=tid%14), 4 px each
    const int y = tid / 14, xq = tid - y*14;
    const int x0 = xq * 4;
    const int ky0 = (y & 1) ? 0 : 1;
    const int iy0 = (y + 1 - ky0) >> 1;   // valid if <28
    const int iy1 = iy0 - 1;              // valid if >=0
    const bool v0 = (iy0 < 28), v1 = (iy1 >= 0);
    const int ixb = (x0 >> 1) - 1;        // input col for j=0
    float acc[4];
    const float bias = b3[0];
    #pragma unroll
    for (int x = 0; x < 4; x++) acc[x] = bias;
    #pragma unroll 1
    for (int i = 0; i < 32; i++) {
      const float* wr = &W3s[i*16 + ky0*4];
      float wa[4], wb[4];
      #pragma unroll
      for (int k = 0; k < 4; k++) { wa[k] = wr[k]; wb[k] = wr[8 + k]; }
      const float* Ci = lds + i*CS_C;
      float r0[4], r1[4];
      #pragma unroll
      for (int j = 0; j < 4; j++) {
        const int ix = ixb + j;
        const bool vx = (ix >= 0) && (ix < 28);
        r0[j] = (v0 && vx) ? Ci[iy0*28 + ix] : 0.0f;
        r1[j] = (v1 && vx) ? Ci[iy1*28 + ix] : 0.0f;
      }
      #pragma unroll
      for (int xl = 0; xl < 4; xl++) {
        const int kxs = (xl & 1) ? 0 : 1;     // x0 even
        const int j = ((x0 + xl + 1 - kxs) >> 1) - ixb;   // 1..3
        float s = acc[xl];
        s = fmaf(r0[j],   wa[kxs],   s);
        s = fmaf(r1[j],   wb[kxs],   s);
        s = fmaf(r0[j-1], wa[kxs+2], s);
        s = fmaf(r1[j-1], wb[kxs+2], s);
        acc[xl] = s;
      }
    }
    *(float4*)(&Ds[y*56 + x0]) = make_float4(acc[0],acc[1],acc[2],acc[3]);
  }
  __syncthreads();

  // ---- bilinear resize 56->84 (half-pixel, edge clamp) + tanh ----
  for (int p = tid; p < 84*84; p += DF_T) {
    const int oy = p / 84, ox = p - oy*84;
    const float sy = (oy + 0.5f)*(2.0f/3.0f) - 0.5f;
    const float sx = (ox + 0.5f)*(2.0f/3.0f) - 0.5f;
    const int y0 = (int)floorf(sy), x0i = (int)floorf(sx);
    const float fy = sy - (float)y0, fx = sx - (float)x0i;
    const int y0c = y0 < 0 ? 0 : y0, y1c = (y0 + 1 > 55) ? 55 : (y0 + 1);
    const int x0c = x0i < 0 ? 0 : x0i, x1c = (x0i + 1 > 55) ? 55 : (x0i + 1);
    const float v00 = Ds[y0c*56 + x0c], v01 = Ds[y0c*56 + x1c];
    const float v10 = Ds[y1c*56 + x0c], v11 = Ds[y1c*56 + x1c];
    const float v = (v00*(1.0f - fx) + v01*fx)*(1.0f - fy)
                  + (v10*(1.0f - fx) + v11*fx)*fy;
    out[(size_t)bg*7056 + p] = tanhf(v);
  }
}

// ================================ launch ====================================
extern "C" void kernel_launch(void* const* d_in, const int* in_sizes, int n_in,
                              void* d_out, int out_size, void* d_ws, size_t ws_size,
                              hipStream_t stream) {
  (void)in_sizes; (void)n_in; (void)out_size; (void)ws_size;
  const float* z  = (const float*)d_in[0];
  const float* cb = (const float*)d_in[1];
  const float* lw = (const float*)d_in[2];
  const float* lb = (const float*)d_in[3];
  const float* w1 = (const float*)d_in[4];
  const float* b1 = (const float*)d_in[5];
  const float* w2 = (const float*)d_in[6];
  const float* b2 = (const float*)d_in[7];
  const float* w3 = (const float*)d_in[8];
  const float* b3 = (const float*)d_in[9];

  float* out      = (float*)d_out;
  float* out_idx  = out + RECON_N;          // 4096 indices as float
  float* out_loss = out + RECON_N + 4096;   // 2 losses

  char*   ws     = (char*)d_ws;
  double* lpart  = (double*)ws;             // 256 doubles
  int*    idx_ws = (int*)(ws + 4096);       // 4096 ints
  float*  x1p    = (float*)(ws + 32768);    // 4096*4096 floats padded (67 MB)

  vq_kernel<<<256, 1024, 0, stream>>>(z, cb, idx_ws, out_idx, lpart);
  fin_kernel<<<1, 256, 0, stream>>>(lpart, out_loss);
  linear_kernel<<<dim3(64, 49), 256, 0, stream>>>(cb, idx_ws, lw, lb, x1p);

  const int df_lds = DF_LDS_FL*4;          // 115200 B
  hipFuncSetAttribute((const void*)decoder_f,
                      hipFuncAttributeMaxDynamicSharedMemorySize, df_lds);
  decoder_f<<<B_SZ, DF_T, df_lds, stream>>>(x1p, w1, b1, w2, b2, w3, b3, out);
}